// Round 16
// baseline (115.360 us; speedup 1.0000x reference)
//
#include <hip/hip_runtime.h>
#include <hip/hip_bf16.h>

// Shapes: B=8, C=256, H=W=64 -> N=4096, r=32. 64 key/query tiles of 64.
// ws: qa (B,64,4,64,8) us | ka (B,64,4,64,8) us | Wall (320,256) us | vt8 (B,64,256,64) fp8
// projmm: grid (5, N/64, B) -- the 5 o-blocks of a tile dispatch ADJACENTLY so
// the 5x redundant x-tile reads hit the same XCD's L2. q pre-scaled by
// scale*log2(e) so attn softmax uses raw v_exp_f32 (exp2) -- identical math.
// attn: r13 structure (counted-vmcnt pipeline, fixed-max softmax, fp8 PV).

typedef float  f32x4   __attribute__((ext_vector_type(4)));
typedef short  short8  __attribute__((ext_vector_type(8)));
typedef unsigned short ushort4v __attribute__((ext_vector_type(4)));
typedef unsigned short ushort8v __attribute__((ext_vector_type(8)));

__device__ __forceinline__ unsigned short f2bf(float f) {
    __hip_bfloat16 h = __float2bfloat16(f);
    return __builtin_bit_cast(unsigned short, h);
}

// ---------------- W concat + convert: wq|wk|wv -> Wall (320,256) bf16 ----------------
__global__ __launch_bounds__(256) void wconv_kernel(
    const float* __restrict__ wq, const float* __restrict__ wk,
    const float* __restrict__ wv, unsigned short* __restrict__ Wall)
{
    int i4 = blockIdx.x * 256 + threadIdx.x;
    int e = i4 * 4;
    const float* src; int off;
    if (e < 8192)       { src = wq; off = e; }
    else if (e < 16384) { src = wk; off = e - 8192; }
    else                { src = wv; off = e - 16384; }
    f32x4 v = *(const f32x4*)(src + off);
    ushort4v u;
#pragma unroll
    for (int j = 0; j < 4; ++j) u[j] = f2bf(v[j]);
    *(ushort4v*)(Wall + e) = u;
}

// ---------------- fused transpose + QKV projection GEMM (bf16 MFMA), o-split ----------------
// xs stride 264 us (132 dw = 4 mod 32 -> 2-way-free B-frag reads); 16B-aligned rows.
__global__ __launch_bounds__(256) void projmm_kernel(
    const float* __restrict__ x,             // (B,256,N) f32
    const unsigned short* __restrict__ Wall, // (320,256)
    const float* __restrict__ bq, const float* __restrict__ bk,
    const float* __restrict__ bv,
    unsigned short* __restrict__ qa,         // (B,64,4,64,8)
    unsigned short* __restrict__ ka,         // (B,64,4,64,8)
    unsigned char* __restrict__ vt8,         // (B,64,256,64) fp8
    int N, float scale)
{
    __shared__ __align__(16) unsigned short xs[64 * 264];      // [n][c] bf16
    __shared__ __align__(16) unsigned short ws2[2][64 * 136];  // W tiles (dbuf)

    const int t  = threadIdx.x;
    const int l  = t & 63;
    const int w  = t >> 6;
    const int qi = l & 15;
    const int g  = l >> 4;
    const int ob = blockIdx.x;          // o-block 0..4 (fastest -> L2 reuse of x-tile)
    const int n0 = blockIdx.y * 64;
    const int b  = blockIdx.z;
    const int tile = n0 >> 6;

    // ---- stage x transposed: thread (w,l) covers n=l, c in [w*64,(w+1)*64)
    {
        const float* xb = x + ((size_t)b * 256 + w * 64) * N + n0 + l;
        unsigned short* dst = xs + l * 264 + w * 64;
#pragma unroll
        for (int i = 0; i < 8; ++i) {
            ushort8v u;
#pragma unroll
            for (int j = 0; j < 8; ++j)
                u[j] = f2bf(xb[(size_t)(i * 8 + j) * N]);
            *(ushort8v*)(dst + i * 8) = u;
        }
    }

    // W staging for this o-block, K-half kp -> ws2[pb]
    auto stageW = [&](int pb, int kp) {
        for (int it = w; it < 17; it += 4) {
            unsigned short* lbase = ws2[pb] + it * 512;
            int ch  = it * 64 + l;
            int row = ch / 17;
            int c16 = ch - row * 17;
            int cc  = c16 > 15 ? 15 : c16;
            const unsigned short* src = Wall + (size_t)(ob * 64 + row) * 256 + kp * 128 + cc * 8;
            __builtin_amdgcn_global_load_lds(
                (const __attribute__((address_space(1))) unsigned int*)src,
                (__attribute__((address_space(3))) unsigned int*)lbase, 16, 0, 0);
        }
    };

    const f32x4 zero4 = {0.f, 0.f, 0.f, 0.f};
    f32x4 acc[4];
#pragma unroll
    for (int nf = 0; nf < 4; ++nf) acc[nf] = zero4;

    stageW(0, 0);
    __syncthreads();   // xs writes + W kp=0 loads complete

    for (int kp = 0; kp < 2; ++kp) {
        if (kp == 0) stageW(1, 1);

        const unsigned short* wsb = ws2[kp];
#pragma unroll
        for (int ks = 0; ks < 4; ++ks) {
            short8 af;
            {
                const unsigned short* ap = wsb + (w * 16 + qi) * 136 + ks * 32 + g * 4;
                ushort4v lo = *(const ushort4v*)ap;
                ushort4v hi = *(const ushort4v*)(ap + 16);
#pragma unroll
                for (int j = 0; j < 4; ++j) { af[j] = (short)lo[j]; af[4 + j] = (short)hi[j]; }
            }
#pragma unroll
            for (int nf = 0; nf < 4; ++nf) {
                short8 bf;
                const unsigned short* bp = xs + (nf * 16 + qi) * 264 + kp * 128 + ks * 32 + g * 4;
                ushort4v lo = *(const ushort4v*)bp;
                ushort4v hi = *(const ushort4v*)(bp + 16);
#pragma unroll
                for (int j = 0; j < 4; ++j) { bf[j] = (short)lo[j]; bf[4 + j] = (short)hi[j]; }
                acc[nf] = __builtin_amdgcn_mfma_f32_16x16x32_bf16(af, bf, acc[nf], 0, 0, 0);
            }
        }
        if (kp == 0) __syncthreads();   // W kp=1 loads complete
    }

    // epilogue: D row = o (= w*16+g*4+j), col = n0+nf*16+qi
    if (ob == 0) {
        const float* bias = (w < 2) ? bq : bk;
        float sc = (w < 2) ? scale : 1.0f;
        unsigned short* dst = (w < 2) ? qa : ka;
#pragma unroll
        for (int nf = 0; nf < 4; ++nf) {
            ushort4v u;
#pragma unroll
            for (int j = 0; j < 4; ++j) {
                int r = (w & 1) * 16 + g * 4 + j;
                u[j] = f2bf((acc[nf][j] + bias[r]) * sc);
            }
            *(ushort4v*)(dst + ((((size_t)b * 64 + tile) * 4 + nf) * 64 + g * 16 + qi) * 8 + (w & 1) * 4) = u;
        }
    } else {
        unsigned char* vtb = vt8 + ((size_t)b * 64 + tile) * 16384;
#pragma unroll
        for (int nf = 0; nf < 4; ++nf) {
            int m = nf * 16 + qi;
            int G   = ((m & 32) ? 4 : 0) + ((m >> 2) & 3);
            int pos = ((m >> 4) & 1) * 4 + (m & 3);
#pragma unroll
            for (int j = 0; j < 4; ++j) {
                int c = (ob - 1) * 64 + w * 16 + g * 4 + j;
                int r = __builtin_amdgcn_cvt_pk_fp8_f32(acc[nf][j] + bv[c], 0.f, 0, false);
                vtb[(size_t)c * 64 + ((G ^ ((c >> 1) & 7)) << 3) + pos] = (unsigned char)(r & 0xFF);
            }
        }
    }
}

// ---------------- flash attention: bf16 QK^T + fp8 PV, counted-vmcnt pipeline ----------------
// q pre-scaled by log2(e) -> p = exp2(s) via raw v_exp_f32 (no v_mul in chain).
__global__ __launch_bounds__(512, 4) void attn_kernel(
    const float* __restrict__ x,            // (B,C,N) f32
    const unsigned short* __restrict__ qa,  // (B,64,4,64,8)
    const unsigned short* __restrict__ ka,  // (B,64,4,64,8)
    const unsigned char* __restrict__ vt8,  // (B,64,256,64) fp8
    const float* __restrict__ gamma,
    float* __restrict__ out, int C, int N)
{
    __shared__ __align__(16) unsigned char vs[4][20480];  // 80KB

    const int t  = threadIdx.x;
    const int l  = t & 63;
    const int w  = t >> 6;
    const int qi = l & 15;
    const int g  = l >> 4;
    const int qg = w & 3;
    const int kh = w >> 2;
    const int tile_q = blockIdx.x;
    const int b  = blockIdx.y;

    const f32x4 zero4 = {0.f, 0.f, 0.f, 0.f};

    short8 qfrag = *(const short8*)(
        qa + ((((size_t)b * 64 + tile_q) * 4 + qg) * 64 + l) * 8);

    const unsigned char* kab_b = (const unsigned char*)(ka + ((size_t)b * 64) * 2048);
    const unsigned char* vtb   = vt8 + ((size_t)b * 64) * 16384;

    auto stage = [&](int buf, int tl) {
        const unsigned char* vsrc = vtb + (size_t)tl * 16384 + w * 2048 + l * 16;
        unsigned char* vdst = &vs[buf][w * 2048 + l * 16];
        __builtin_amdgcn_global_load_lds(
            (const __attribute__((address_space(1))) unsigned int*)vsrc,
            (__attribute__((address_space(3))) unsigned int*)vdst, 16, 0, 0);
        __builtin_amdgcn_global_load_lds(
            (const __attribute__((address_space(1))) unsigned int*)(vsrc + 1024),
            (__attribute__((address_space(3))) unsigned int*)(vdst + 1024), 16, 0, 0);
        const unsigned char* ksrc = kab_b + (size_t)tl * 4096 + w * 512 + l * 4;
        unsigned char* kdst = &vs[buf][16384 + w * 512 + l * 4];
        __builtin_amdgcn_global_load_lds(
            (const __attribute__((address_space(1))) unsigned int*)ksrc,
            (__attribute__((address_space(3))) unsigned int*)kdst, 4, 0, 0);
        __builtin_amdgcn_global_load_lds(
            (const __attribute__((address_space(1))) unsigned int*)(ksrc + 256),
            (__attribute__((address_space(3))) unsigned int*)(kdst + 256), 4, 0, 0);
    };

    f32x4 o_[16];
#pragma unroll
    for (int cf = 0; cf < 16; ++cf) o_[cf] = zero4;
    float lsum = 0.f;
    long acur = 0;

    auto packP = [&](const f32x4& s0, const f32x4& s1) -> long {
        float p[8];
#pragma unroll
        for (int j = 0; j < 4; ++j) {
            p[j]     = __builtin_amdgcn_exp2f(s0[j]);
            p[4 + j] = __builtin_amdgcn_exp2f(s1[j]);
        }
#pragma unroll
        for (int j = 0; j < 8; ++j) lsum += p[j];
        int w0 = __builtin_amdgcn_cvt_pk_fp8_f32(p[0], p[1], 0, false);
        w0 = __builtin_amdgcn_cvt_pk_fp8_f32(p[2], p[3], w0, true);
        int w1 = __builtin_amdgcn_cvt_pk_fp8_f32(p[4], p[5], 0, false);
        w1 = __builtin_amdgcn_cvt_pk_fp8_f32(p[6], p[7], w1, true);
        return (long)(((unsigned long long)(unsigned int)w0) |
                      ((unsigned long long)(unsigned int)w1 << 32));
    };

    const int voff = (((kh << 2) | g) ^ ((qi >> 1) & 7)) << 3;
    auto pv = [&](int buf) {
        const unsigned char* vrow = &vs[buf][qi * 64 + voff];
#pragma unroll
        for (int cf = 0; cf < 16; ++cf) {
            long v8 = *(const long*)(vrow + cf * 1024);
            o_[cf] = __builtin_amdgcn_mfma_f32_16x16x32_fp8_fp8(acur, v8, o_[cf], 0, 0, 0);
        }
    };

    stage(0, 0);
    stage(1, 1);

    for (int tl = 0; tl < 64; ++tl) {
        asm volatile("s_waitcnt vmcnt(4)\n\ts_barrier" ::: "memory");
        __builtin_amdgcn_sched_barrier(0);

        if (tl < 62) stage((tl + 2) & 3, tl + 2);

        const unsigned char* kb2 = &vs[tl & 3][16384 + kh * 2048 + l * 16];
        short8 kf0 = *(const short8*)kb2;
        short8 kf1 = *(const short8*)(kb2 + 1024);
        f32x4 s0 = __builtin_amdgcn_mfma_f32_16x16x32_bf16(kf0, qfrag, zero4, 0, 0, 0);
        f32x4 s1 = __builtin_amdgcn_mfma_f32_16x16x32_bf16(kf1, qfrag, zero4, 0, 0, 0);

        if (tl) pv((tl - 1) & 3);

        acur = packP(s0, s1);
    }
    pv(3);

    float l_run = lsum;
    l_run += __shfl_xor(l_run, 16);
    l_run += __shfl_xor(l_run, 32);

    __syncthreads();
    float* cbuf = (float*)vs;
    float* lex  = cbuf + 8192;
    const int lx = l & 31;
    float* bp = cbuf + ((qg * 64) + l) * 32;
    if (kh == 1) {
        lex[qg * 64 + l] = l_run;
#pragma unroll
        for (int cf = 0; cf < 8; ++cf)
#pragma unroll
            for (int j = 0; j < 4; ++j) bp[(cf * 4 + j) ^ lx] = o_[cf][j];
    }
    __syncthreads();

    float cj[4];
    const float gm = gamma[0];
    const float* xb = x + (size_t)b * C * N;
    float* ob = out + (size_t)b * C * N;
    const int ncol = tile_q * 64 + qg * 16 + g * 4;

    if (kh == 0) {
        float lt = l_run + lex[qg * 64 + l];
        float c0 = gm / lt;
#pragma unroll
        for (int j = 0; j < 4; ++j) cj[j] = __shfl(c0, g * 4 + j);
#pragma unroll
        for (int cf = 0; cf < 8; ++cf) {
            int c = cf * 16 + qi;
            f32x4 xv = *(const f32x4*)(xb + (size_t)c * N + ncol);
            f32x4 ov;
#pragma unroll
            for (int j = 0; j < 4; ++j)
                ov[j] = xv[j] + (o_[cf][j] + bp[(cf * 4 + j) ^ lx]) * cj[j];
            *(f32x4*)(ob + (size_t)c * N + ncol) = ov;
        }
    }
    __syncthreads();

    if (kh == 1) {
#pragma unroll
        for (int cf = 0; cf < 8; ++cf)
#pragma unroll
            for (int j = 0; j < 4; ++j) bp[(cf * 4 + j) ^ lx] = o_[8 + cf][j];
    }
    __syncthreads();

    if (kh == 0) {
#pragma unroll
        for (int cf = 0; cf < 8; ++cf) {
            int c = (8 + cf) * 16 + qi;
            f32x4 xv = *(const f32x4*)(xb + (size_t)c * N + ncol);
            f32x4 ov;
#pragma unroll
            for (int j = 0; j < 4; ++j)
                ov[j] = xv[j] + (o_[8 + cf][j] + bp[(cf * 4 + j) ^ lx]) * cj[j];
            *(f32x4*)(ob + (size_t)c * N + ncol) = ov;
        }
    }
}

extern "C" void kernel_launch(void* const* d_in, const int* in_sizes, int n_in,
                              void* d_out, int out_size, void* d_ws, size_t ws_size,
                              hipStream_t stream) {
    const float* x     = (const float*)d_in[0];
    const float* wq    = (const float*)d_in[1];
    const float* bq    = (const float*)d_in[2];
    const float* wk    = (const float*)d_in[3];
    const float* bk    = (const float*)d_in[4];
    const float* wv    = (const float*)d_in[5];
    const float* bv    = (const float*)d_in[6];
    const float* gamma = (const float*)d_in[7];
    float* out = (float*)d_out;

    const int B = 8, C = 256, N = 4096;
    // 1/sqrt(32) * log2(e): q pre-scaled so softmax uses exp2 directly
    const float scale = 0.17677669529663687f * 1.4426950408889634f;

    unsigned short* qa   = (unsigned short*)d_ws;               // 2MB
    unsigned short* ka   = qa + (size_t)B * 64 * 4 * 64 * 8;    // 2MB
    unsigned short* Wall = ka + (size_t)B * 64 * 4 * 64 * 8;    // 160KB
    unsigned char*  vt8  = (unsigned char*)(Wall + 81920);      // 8MB

    wconv_kernel<<<80, 256, 0, stream>>>(wq, wk, wv, Wall);
    projmm_kernel<<<dim3(5, N / 64, B), 256, 0, stream>>>(
        x, Wall, bq, bk, bv, qa, ka, vt8, N, scale);
    attn_kernel<<<dim3(N / 64, B), 512, 0, stream>>>(x, qa, ka, vt8, gamma, out, C, N);
}

// Round 18
// 102.950 us; speedup vs baseline: 1.1205x; 1.1205x over previous
//
#include <hip/hip_runtime.h>
#include <hip/hip_bf16.h>

// Shapes: B=8, C=256, H=W=64 -> N=4096, r=32. 64 key/query tiles of 64.
// ws: qa (B,64,4,64,8) us | ka (B,64,4,64,8) us | Wall (320,256) us | vt8 (B,64,256,64) fp8
// projmm: grid (N/64, 5, B) -- the 5 o-blocks of a tile are 64 dispatch slots
// apart = SAME XCD (round-robin mod 8), so redundant x-tile reads are L2 hits.
// q pre-scaled by scale*log2(e) so softmax uses raw v_exp_f32 (exp2).
// attn: r13 structure (counted-vmcnt pipeline, fixed-max softmax, fp8 PV).

typedef float  f32x4   __attribute__((ext_vector_type(4)));
typedef short  short8  __attribute__((ext_vector_type(8)));
typedef unsigned short ushort4v __attribute__((ext_vector_type(4)));
typedef unsigned short ushort8v __attribute__((ext_vector_type(8)));

__device__ __forceinline__ unsigned short f2bf(float f) {
    __hip_bfloat16 h = __float2bfloat16(f);
    return __builtin_bit_cast(unsigned short, h);
}

// ---------------- W concat + convert: wq|wk|wv -> Wall (320,256) bf16 ----------------
__global__ __launch_bounds__(256) void wconv_kernel(
    const float* __restrict__ wq, const float* __restrict__ wk,
    const float* __restrict__ wv, unsigned short* __restrict__ Wall)
{
    int i4 = blockIdx.x * 256 + threadIdx.x;
    int e = i4 * 4;
    const float* src; int off;
    if (e < 8192)       { src = wq; off = e; }
    else if (e < 16384) { src = wk; off = e - 8192; }
    else                { src = wv; off = e - 16384; }
    f32x4 v = *(const f32x4*)(src + off);
    ushort4v u;
#pragma unroll
    for (int j = 0; j < 4; ++j) u[j] = f2bf(v[j]);
    *(ushort4v*)(Wall + e) = u;
}

// ---------------- fused transpose + QKV projection GEMM (bf16 MFMA), o-split ----------------
// xs stride 264 us (132 dw = 4 mod 32 -> 2-way-free B-frag reads); 16B-aligned rows.
__global__ __launch_bounds__(256) void projmm_kernel(
    const float* __restrict__ x,             // (B,256,N) f32
    const unsigned short* __restrict__ Wall, // (320,256)
    const float* __restrict__ bq, const float* __restrict__ bk,
    const float* __restrict__ bv,
    unsigned short* __restrict__ qa,         // (B,64,4,64,8)
    unsigned short* __restrict__ ka,         // (B,64,4,64,8)
    unsigned char* __restrict__ vt8,         // (B,64,256,64) fp8
    int N, float scale)
{
    __shared__ __align__(16) unsigned short xs[64 * 264];      // [n][c] bf16
    __shared__ __align__(16) unsigned short ws2[2][64 * 136];  // W tiles (dbuf)

    const int t  = threadIdx.x;
    const int l  = t & 63;
    const int w  = t >> 6;
    const int qi = l & 15;
    const int g  = l >> 4;
    const int n0 = blockIdx.x * 64;
    const int ob = blockIdx.y;          // o-block 0..4 (64 slots apart = same XCD)
    const int b  = blockIdx.z;
    const int tile = n0 >> 6;

    // ---- stage x transposed: thread (w,l) covers n=l, c in [w*64,(w+1)*64)
    {
        const float* xb = x + ((size_t)b * 256 + w * 64) * N + n0 + l;
        unsigned short* dst = xs + l * 264 + w * 64;
#pragma unroll
        for (int i = 0; i < 8; ++i) {
            ushort8v u;
#pragma unroll
            for (int j = 0; j < 8; ++j)
                u[j] = f2bf(xb[(size_t)(i * 8 + j) * N]);
            *(ushort8v*)(dst + i * 8) = u;
        }
    }

    // W staging for this o-block, K-half kp -> ws2[pb]
    auto stageW = [&](int pb, int kp) {
        for (int it = w; it < 17; it += 4) {
            unsigned short* lbase = ws2[pb] + it * 512;
            int ch  = it * 64 + l;
            int row = ch / 17;
            int c16 = ch - row * 17;
            int cc  = c16 > 15 ? 15 : c16;
            const unsigned short* src = Wall + (size_t)(ob * 64 + row) * 256 + kp * 128 + cc * 8;
            __builtin_amdgcn_global_load_lds(
                (const __attribute__((address_space(1))) unsigned int*)src,
                (__attribute__((address_space(3))) unsigned int*)lbase, 16, 0, 0);
        }
    };

    const f32x4 zero4 = {0.f, 0.f, 0.f, 0.f};
    f32x4 acc[4];
#pragma unroll
    for (int nf = 0; nf < 4; ++nf) acc[nf] = zero4;

    stageW(0, 0);
    __syncthreads();   // xs writes + W kp=0 loads complete

    for (int kp = 0; kp < 2; ++kp) {
        if (kp == 0) stageW(1, 1);

        const unsigned short* wsb = ws2[kp];
#pragma unroll
        for (int ks = 0; ks < 4; ++ks) {
            short8 af;
            {
                const unsigned short* ap = wsb + (w * 16 + qi) * 136 + ks * 32 + g * 4;
                ushort4v lo = *(const ushort4v*)ap;
                ushort4v hi = *(const ushort4v*)(ap + 16);
#pragma unroll
                for (int j = 0; j < 4; ++j) { af[j] = (short)lo[j]; af[4 + j] = (short)hi[j]; }
            }
#pragma unroll
            for (int nf = 0; nf < 4; ++nf) {
                short8 bf;
                const unsigned short* bp = xs + (nf * 16 + qi) * 264 + kp * 128 + ks * 32 + g * 4;
                ushort4v lo = *(const ushort4v*)bp;
                ushort4v hi = *(const ushort4v*)(bp + 16);
#pragma unroll
                for (int j = 0; j < 4; ++j) { bf[j] = (short)lo[j]; bf[4 + j] = (short)hi[j]; }
                acc[nf] = __builtin_amdgcn_mfma_f32_16x16x32_bf16(af, bf, acc[nf], 0, 0, 0);
            }
        }
        if (kp == 0) __syncthreads();   // W kp=1 loads complete
    }

    // epilogue: D row = o (= w*16+g*4+j), col = n0+nf*16+qi
    if (ob == 0) {
        const float* bias = (w < 2) ? bq : bk;
        float sc = (w < 2) ? scale : 1.0f;
        unsigned short* dst = (w < 2) ? qa : ka;
#pragma unroll
        for (int nf = 0; nf < 4; ++nf) {
            ushort4v u;
#pragma unroll
            for (int j = 0; j < 4; ++j) {
                int r = (w & 1) * 16 + g * 4 + j;
                u[j] = f2bf((acc[nf][j] + bias[r]) * sc);
            }
            *(ushort4v*)(dst + ((((size_t)b * 64 + tile) * 4 + nf) * 64 + g * 16 + qi) * 8 + (w & 1) * 4) = u;
        }
    } else {
        unsigned char* vtb = vt8 + ((size_t)b * 64 + tile) * 16384;
#pragma unroll
        for (int nf = 0; nf < 4; ++nf) {
            int m = nf * 16 + qi;
            int G   = ((m & 32) ? 4 : 0) + ((m >> 2) & 3);
            int pos = ((m >> 4) & 1) * 4 + (m & 3);
#pragma unroll
            for (int j = 0; j < 4; ++j) {
                int c = (ob - 1) * 64 + w * 16 + g * 4 + j;
                int r = __builtin_amdgcn_cvt_pk_fp8_f32(acc[nf][j] + bv[c], 0.f, 0, false);
                vtb[(size_t)c * 64 + ((G ^ ((c >> 1) & 7)) << 3) + pos] = (unsigned char)(r & 0xFF);
            }
        }
    }
}

// ---------------- flash attention: bf16 QK^T + fp8 PV, counted-vmcnt pipeline ----------------
// q pre-scaled by log2(e) -> p = exp2(s) via raw v_exp_f32 (no v_mul in chain).
__global__ __launch_bounds__(512, 4) void attn_kernel(
    const float* __restrict__ x,            // (B,C,N) f32
    const unsigned short* __restrict__ qa,  // (B,64,4,64,8)
    const unsigned short* __restrict__ ka,  // (B,64,4,64,8)
    const unsigned char* __restrict__ vt8,  // (B,64,256,64) fp8
    const float* __restrict__ gamma,
    float* __restrict__ out, int C, int N)
{
    __shared__ __align__(16) unsigned char vs[4][20480];  // 80KB

    const int t  = threadIdx.x;
    const int l  = t & 63;
    const int w  = t >> 6;
    const int qi = l & 15;
    const int g  = l >> 4;
    const int qg = w & 3;
    const int kh = w >> 2;
    const int tile_q = blockIdx.x;
    const int b  = blockIdx.y;

    const f32x4 zero4 = {0.f, 0.f, 0.f, 0.f};

    short8 qfrag = *(const short8*)(
        qa + ((((size_t)b * 64 + tile_q) * 4 + qg) * 64 + l) * 8);

    const unsigned char* kab_b = (const unsigned char*)(ka + ((size_t)b * 64) * 2048);
    const unsigned char* vtb   = vt8 + ((size_t)b * 64) * 16384;

    auto stage = [&](int buf, int tl) {
        const unsigned char* vsrc = vtb + (size_t)tl * 16384 + w * 2048 + l * 16;
        unsigned char* vdst = &vs[buf][w * 2048 + l * 16];
        __builtin_amdgcn_global_load_lds(
            (const __attribute__((address_space(1))) unsigned int*)vsrc,
            (__attribute__((address_space(3))) unsigned int*)vdst, 16, 0, 0);
        __builtin_amdgcn_global_load_lds(
            (const __attribute__((address_space(1))) unsigned int*)(vsrc + 1024),
            (__attribute__((address_space(3))) unsigned int*)(vdst + 1024), 16, 0, 0);
        const unsigned char* ksrc = kab_b + (size_t)tl * 4096 + w * 512 + l * 4;
        unsigned char* kdst = &vs[buf][16384 + w * 512 + l * 4];
        __builtin_amdgcn_global_load_lds(
            (const __attribute__((address_space(1))) unsigned int*)ksrc,
            (__attribute__((address_space(3))) unsigned int*)kdst, 4, 0, 0);
        __builtin_amdgcn_global_load_lds(
            (const __attribute__((address_space(1))) unsigned int*)(ksrc + 256),
            (__attribute__((address_space(3))) unsigned int*)(kdst + 256), 4, 0, 0);
    };

    f32x4 o_[16];
#pragma unroll
    for (int cf = 0; cf < 16; ++cf) o_[cf] = zero4;
    float lsum = 0.f;
    long acur = 0;

    auto packP = [&](const f32x4& s0, const f32x4& s1) -> long {
        float p[8];
#pragma unroll
        for (int j = 0; j < 4; ++j) {
            p[j]     = __builtin_amdgcn_exp2f(s0[j]);
            p[4 + j] = __builtin_amdgcn_exp2f(s1[j]);
        }
#pragma unroll
        for (int j = 0; j < 8; ++j) lsum += p[j];
        int w0 = __builtin_amdgcn_cvt_pk_fp8_f32(p[0], p[1], 0, false);
        w0 = __builtin_amdgcn_cvt_pk_fp8_f32(p[2], p[3], w0, true);
        int w1 = __builtin_amdgcn_cvt_pk_fp8_f32(p[4], p[5], 0, false);
        w1 = __builtin_amdgcn_cvt_pk_fp8_f32(p[6], p[7], w1, true);
        return (long)(((unsigned long long)(unsigned int)w0) |
                      ((unsigned long long)(unsigned int)w1 << 32));
    };

    const int voff = (((kh << 2) | g) ^ ((qi >> 1) & 7)) << 3;
    auto pv = [&](int buf) {
        const unsigned char* vrow = &vs[buf][qi * 64 + voff];
#pragma unroll
        for (int cf = 0; cf < 16; ++cf) {
            long v8 = *(const long*)(vrow + cf * 1024);
            o_[cf] = __builtin_amdgcn_mfma_f32_16x16x32_fp8_fp8(acur, v8, o_[cf], 0, 0, 0);
        }
    };

    stage(0, 0);
    stage(1, 1);

    for (int tl = 0; tl < 64; ++tl) {
        asm volatile("s_waitcnt vmcnt(4)\n\ts_barrier" ::: "memory");
        __builtin_amdgcn_sched_barrier(0);

        if (tl < 62) stage((tl + 2) & 3, tl + 2);

        const unsigned char* kb2 = &vs[tl & 3][16384 + kh * 2048 + l * 16];
        short8 kf0 = *(const short8*)kb2;
        short8 kf1 = *(const short8*)(kb2 + 1024);
        f32x4 s0 = __builtin_amdgcn_mfma_f32_16x16x32_bf16(kf0, qfrag, zero4, 0, 0, 0);
        f32x4 s1 = __builtin_amdgcn_mfma_f32_16x16x32_bf16(kf1, qfrag, zero4, 0, 0, 0);

        if (tl) pv((tl - 1) & 3);

        acur = packP(s0, s1);
    }
    pv(3);

    float l_run = lsum;
    l_run += __shfl_xor(l_run, 16);
    l_run += __shfl_xor(l_run, 32);

    __syncthreads();
    float* cbuf = (float*)vs;
    float* lex  = cbuf + 8192;
    const int lx = l & 31;
    float* bp = cbuf + ((qg * 64) + l) * 32;
    if (kh == 1) {
        lex[qg * 64 + l] = l_run;
#pragma unroll
        for (int cf = 0; cf < 8; ++cf)
#pragma unroll
            for (int j = 0; j < 4; ++j) bp[(cf * 4 + j) ^ lx] = o_[cf][j];
    }
    __syncthreads();

    float cj[4];
    const float gm = gamma[0];
    const float* xb = x + (size_t)b * C * N;
    float* ob = out + (size_t)b * C * N;
    const int ncol = tile_q * 64 + qg * 16 + g * 4;

    if (kh == 0) {
        float lt = l_run + lex[qg * 64 + l];
        float c0 = gm / lt;
#pragma unroll
        for (int j = 0; j < 4; ++j) cj[j] = __shfl(c0, g * 4 + j);
#pragma unroll
        for (int cf = 0; cf < 8; ++cf) {
            int c = cf * 16 + qi;
            f32x4 xv = *(const f32x4*)(xb + (size_t)c * N + ncol);
            f32x4 ov;
#pragma unroll
            for (int j = 0; j < 4; ++j)
                ov[j] = xv[j] + (o_[cf][j] + bp[(cf * 4 + j) ^ lx]) * cj[j];
            *(f32x4*)(ob + (size_t)c * N + ncol) = ov;
        }
    }
    __syncthreads();

    if (kh == 1) {
#pragma unroll
        for (int cf = 0; cf < 8; ++cf)
#pragma unroll
            for (int j = 0; j < 4; ++j) bp[(cf * 4 + j) ^ lx] = o_[8 + cf][j];
    }
    __syncthreads();

    if (kh == 0) {
#pragma unroll
        for (int cf = 0; cf < 8; ++cf) {
            int c = (8 + cf) * 16 + qi;
            f32x4 xv = *(const f32x4*)(xb + (size_t)c * N + ncol);
            f32x4 ov;
#pragma unroll
            for (int j = 0; j < 4; ++j)
                ov[j] = xv[j] + (o_[8 + cf][j] + bp[(cf * 4 + j) ^ lx]) * cj[j];
            *(f32x4*)(ob + (size_t)c * N + ncol) = ov;
        }
    }
}

extern "C" void kernel_launch(void* const* d_in, const int* in_sizes, int n_in,
                              void* d_out, int out_size, void* d_ws, size_t ws_size,
                              hipStream_t stream) {
    const float* x     = (const float*)d_in[0];
    const float* wq    = (const float*)d_in[1];
    const float* bq    = (const float*)d_in[2];
    const float* wk    = (const float*)d_in[3];
    const float* bk    = (const float*)d_in[4];
    const float* wv    = (const float*)d_in[5];
    const float* bv    = (const float*)d_in[6];
    const float* gamma = (const float*)d_in[7];
    float* out = (float*)d_out;

    const int B = 8, C = 256, N = 4096;
    // 1/sqrt(32) * log2(e): q pre-scaled so softmax uses exp2 directly
    const float scale = 0.17677669529663687f * 1.4426950408889634f;

    unsigned short* qa   = (unsigned short*)d_ws;               // 2MB
    unsigned short* ka   = qa + (size_t)B * 64 * 4 * 64 * 8;    // 2MB
    unsigned short* Wall = ka + (size_t)B * 64 * 4 * 64 * 8;    // 160KB
    unsigned char*  vt8  = (unsigned char*)(Wall + 81920);      // 8MB

    wconv_kernel<<<80, 256, 0, stream>>>(wq, wk, wv, Wall);
    projmm_kernel<<<dim3(N / 64, 5, B), 256, 0, stream>>>(
        x, Wall, bq, bk, bv, qa, ka, vt8, N, scale);
    attn_kernel<<<dim3(N / 64, B), 512, 0, stream>>>(x, qa, ka, vt8, gamma, out, C, N);
}